// Round 12
// baseline (4633.911 us; speedup 1.0000x reference)
//
#include <hip/hip_runtime.h>
#include <cstdint>
#include <cstddef>

// GRU-D: B=64, T=512, D=256, H=1024.
// v11 = v9 (proven, 3.81 ms scan) with ONE local change: probe-then-read
// polling. Retry loop spins on a 1-dword/thread probe (samples every
// producer burst) instead of re-reading the full 32 KB panel -> ~32x less
// poll traffic at the MALL. Full read + full tag verify still gates
// consumption (correctness unchanged). Grid 256, 1 block/CU (hard rule:
// both >256-grid variants deadlocked).

#define NB 64
#define NT 512
#define ND 256
#define NH 1024

typedef _Float16 h2_t __attribute__((ext_vector_type(2)));
typedef _Float16 half8 __attribute__((ext_vector_type(8)));
typedef float f32x4 __attribute__((ext_vector_type(4)));
typedef uint32_t u32x4 __attribute__((ext_vector_type(4)));

__device__ __forceinline__ float fdot2(uint32_t a, uint32_t b, float acc) {
  h2_t ha = __builtin_bit_cast(h2_t, a);
  h2_t hb = __builtin_bit_cast(h2_t, b);
#if __has_builtin(__builtin_amdgcn_fdot2)
  return __builtin_amdgcn_fdot2(ha, hb, acc, false);
#else
  return acc + (float)ha[0] * (float)hb[0] + (float)ha[1] * (float)hb[1];
#endif
}

__device__ __forceinline__ uint32_t pack2(float a, float b) {
  h2_t v; v[0] = (_Float16)a; v[1] = (_Float16)b;
  return __builtin_bit_cast(uint32_t, v);
}
__device__ __forceinline__ uint16_t f2h(float x) {
  _Float16 v = (_Float16)x; return __builtin_bit_cast(uint16_t, v);
}
__device__ __forceinline__ float h2f(uint16_t u) {
  return (float)__builtin_bit_cast(_Float16, u);
}
__device__ __forceinline__ float sigm(float x) {
  return 1.f / (1.f + __expf(-x));
}
__device__ __forceinline__ float fast_tanh(float x) {
  float e = __expf(2.f * x);
  return 1.f - 2.f / (e + 1.f);
}

// device-coherent (bypass L1/L2, served at MALL)
__device__ __forceinline__ uint4 ld_cg_b128(const uint32_t* p) {
  uint4 v;
  asm volatile("global_load_dwordx4 %0, %1, off sc0 sc1" : "=v"(v) : "v"(p) : "memory");
  return v;
}
__device__ __forceinline__ void st_cg_b128(uint32_t* p, u32x4 v) {
  asm volatile("global_store_dwordx4 %0, %1, off sc0 sc1" :: "v"(p), "v"(v) : "memory");
}

// ---- pack kernels ------------------------------------------------------

__global__ void pack_x_k(const float2* __restrict__ x, uint32_t* __restrict__ x2, int n) {
  int stride = gridDim.x * blockDim.x;
  for (int i = blockIdx.x * blockDim.x + threadIdx.x; i < n; i += stride) {
    float2 v = x[i];
    x2[i] = pack2(v.x, v.y);
  }
}

// src [K][1024] f32 -> dst [K/2][1024] f16x2 (pairs along K) — for W
__global__ void pack_rows_k(const float* __restrict__ src, uint32_t* __restrict__ dst, int K) {
  int n = (K >> 1) * NH;
  int stride = gridDim.x * blockDim.x;
  for (int i = blockIdx.x * blockDim.x + threadIdx.x; i < n; i += stride) {
    int kp = i >> 10, j = i & 1023;
    dst[i] = pack2(src[(2 * kp) * NH + j], src[(2 * kp + 1) * NH + j]);
  }
}

// U [1024][1024] f32 -> UT [1024 cols][1024 k] f16. 64x64 LDS tiles.
__global__ __launch_bounds__(256) void transpose_f2h_k(
    const float* __restrict__ src, uint16_t* __restrict__ dst) {
  __shared__ uint16_t lt[64][68];
  int tr = blockIdx.x & 15, tc = blockIdx.x >> 4;
  int tid = threadIdx.x;
  int r0 = tid >> 6, cc = tid & 63;
#pragma unroll
  for (int it = 0; it < 16; ++it) {
    int r = it * 4 + r0;
    lt[cc][r] = f2h(src[(size_t)(tr * 64 + r) * 1024 + tc * 64 + cc]);
  }
  __syncthreads();
#pragma unroll
  for (int it = 0; it < 16; ++it) {
    int c = it * 4 + r0;
    dst[(size_t)(tc * 64 + c) * 1024 + tr * 64 + cc] = lt[c][cc];
  }
}

// ---- phase 1: input projections (proven) -------------------------------
__global__ __launch_bounds__(256) void proj_k(
    const uint32_t* __restrict__ x2, const uint32_t* __restrict__ W2,
    const float* __restrict__ bd, const float* __restrict__ bz,
    const float* __restrict__ br, const float* __restrict__ bh,
    uint16_t* __restrict__ g_gamma, uint16_t* __restrict__ g_xz,
    uint16_t* __restrict__ g_xr, uint16_t* __restrict__ g_xh) {
  __shared__ uint32_t xs[64 * 132];
  int wg = blockIdx.x;
  int rg = wg >> 6;
  int cg = wg & 63;
  int tid = threadIdx.x;

  const uint4* xsrc = (const uint4*)x2 + (size_t)rg * 64 * 32;
#pragma unroll
  for (int w = 0; w < 8; ++w) {
    int f = tid + w * 256;
    int row = f >> 5, q = f & 31;
    *(uint4*)&xs[row * 132 + q * 4] = xsrc[row * 32 + q];
  }
  __syncthreads();

  int a = cg >> 4;
  int j0 = (cg & 15) * 64 + (tid & 15) * 4;
  int tr = tid >> 4;
  const uint32_t* W2a = W2 + (size_t)a * (128 * 1024) + j0;

  float acc[4][4] = {};
#pragma unroll 4
  for (int kp = 0; kp < 128; ++kp) {
    uint32_t xv0 = xs[(tr * 4 + 0) * 132 + kp];
    uint32_t xv1 = xs[(tr * 4 + 1) * 132 + kp];
    uint32_t xv2 = xs[(tr * 4 + 2) * 132 + kp];
    uint32_t xv3 = xs[(tr * 4 + 3) * 132 + kp];
    uint4 wv = *(const uint4*)(W2a + (size_t)kp * 1024);
    acc[0][0] = fdot2(xv0, wv.x, acc[0][0]); acc[0][1] = fdot2(xv0, wv.y, acc[0][1]);
    acc[0][2] = fdot2(xv0, wv.z, acc[0][2]); acc[0][3] = fdot2(xv0, wv.w, acc[0][3]);
    acc[1][0] = fdot2(xv1, wv.x, acc[1][0]); acc[1][1] = fdot2(xv1, wv.y, acc[1][1]);
    acc[1][2] = fdot2(xv1, wv.z, acc[1][2]); acc[1][3] = fdot2(xv1, wv.w, acc[1][3]);
    acc[2][0] = fdot2(xv2, wv.x, acc[2][0]); acc[2][1] = fdot2(xv2, wv.y, acc[2][1]);
    acc[2][2] = fdot2(xv2, wv.z, acc[2][2]); acc[2][3] = fdot2(xv2, wv.w, acc[2][3]);
    acc[3][0] = fdot2(xv3, wv.x, acc[3][0]); acc[3][1] = fdot2(xv3, wv.y, acc[3][1]);
    acc[3][2] = fdot2(xv3, wv.z, acc[3][2]); acc[3][3] = fdot2(xv3, wv.w, acc[3][3]);
  }

  const float* bias = a == 0 ? bd : a == 1 ? bz : a == 2 ? br : bh;
  uint16_t* dst = a == 0 ? g_gamma : a == 1 ? g_xz : a == 2 ? g_xr : g_xh;
  float b0 = bias[j0], b1 = bias[j0 + 1], b2 = bias[j0 + 2], b3 = bias[j0 + 3];
#pragma unroll
  for (int i = 0; i < 4; ++i) {
    int n = rg * 64 + tr * 4 + i;
    int b = n >> 9, t = n & 511;
    float p0 = acc[i][0] + b0, p1 = acc[i][1] + b1;
    float p2 = acc[i][2] + b2, p3 = acc[i][3] + b3;
    if (a == 0) {
      p0 = __expf(-fmaxf(p0, 0.f)); p1 = __expf(-fmaxf(p1, 0.f));
      p2 = __expf(-fmaxf(p2, 0.f)); p3 = __expf(-fmaxf(p3, 0.f));
    }
    uint32_t* o = (uint32_t*)(dst + (((size_t)(t * 64 + b)) << 10) + j0);
    o[0] = pack2(p0, p1);
    o[1] = pack2(p2, p3);
  }
}

// ---- v11 scan (= v9 + probe-then-read polling) -------------------------

__global__ __launch_bounds__(256, 1) void scan_k(
    const uint16_t* __restrict__ UzT, const uint16_t* __restrict__ UrT,
    const uint16_t* __restrict__ UhT,
    const uint16_t* __restrict__ g_gamma, const uint16_t* __restrict__ g_xz,
    const uint16_t* __restrict__ g_xr, const uint16_t* __restrict__ g_xh,
    uint32_t* __restrict__ Hbuf, uint32_t* __restrict__ RHbuf,
    float* __restrict__ out) {
  __shared__ uint16_t Hp[9][1032];   // h_dec panel rows 0-7, row 8 = zeros
  __shared__ uint16_t RHp[9][1032];
  __shared__ float red[4][4][256];
  __shared__ uint32_t pub[8][32];    // tagged publish staging

  const int tid = threadIdx.x;
  const int g = blockIdx.x & 7;
  const int slot = blockIdx.x >> 3;
  const int c0 = slot * 32;
  const int lane = tid & 63, w = tid >> 6;
  const int r16 = lane & 15, q = lane >> 4;

  for (int i = tid; i < 1032; i += 256) { Hp[8][i] = 0; RHp[8][i] = 0; }

  // ---- one-time: B fragments into registers (per wave: K in [w*256,+256))
  half8 Bz[2][8], Br[2][8], Bh[2][8];
#pragma unroll
  for (int ct = 0; ct < 2; ++ct) {
    const size_t colb = (size_t)(c0 + ct * 16 + r16) * 1024 + w * 256 + q * 8;
#pragma unroll
    for (int kc = 0; kc < 8; ++kc) {
      Bz[ct][kc] = *(const half8*)(UzT + colb + kc * 32);
      Br[ct][kc] = *(const half8*)(UrT + colb + kc * 32);
      Bh[ct][kc] = *(const half8*)(UhT + colb + kc * 32);
    }
  }
  __syncthreads();

  const uint16_t* aprow = Hp[r16 < 8 ? r16 : 8];
  const uint16_t* aprow2 = RHp[r16 < 8 ? r16 : 8];
  const int aoff = w * 256 + q * 8;

  // epilogue geometry: wave ct = w&1; rows erow..erow+3 (valid when lane<32)
  const int ect = w & 1;
  const int ecol = c0 + ect * 16 + r16;
  const int erow = q * 4;

  // probe address: thread t samples row (t>>5) of producer slot (t&31) at
  // that producer's last dword of the row (col (t&31)*32 + 31). 256 samples
  // cover all 8 rows x 32 producers.
  const size_t probeoff = ((size_t)g << 13) + (size_t)(tid >> 5) * 1024 +
                          (size_t)(tid & 31) * 32 + 31;

  auto poll_fill = [&](const uint32_t* __restrict__ buf, unsigned exp,
                       uint16_t (&panel)[9][1032]) {
    const uint32_t* base = buf + ((size_t)g << 13) + (size_t)tid * 4;
    const uint32_t* probe = buf + probeoff;
    uint4 sv[8];
    for (;;) {
      // cheap probe spin: 1 dword/thread until all sampled tags match
      for (;;) {
        unsigned pv;
        asm volatile("global_load_dword %0, %1, off sc0 sc1\n\t"
                     "s_waitcnt vmcnt(0)"
                     : "=v"(pv) : "v"(probe) : "memory");
        __builtin_amdgcn_sched_barrier(0);
        if (__all((int)((pv >> 16) == exp))) break;
        __builtin_amdgcn_s_sleep(1);
      }
      // full read + full tag verify (correctness gate)
#pragma unroll
      for (int i = 0; i < 8; ++i) sv[i] = ld_cg_b128(base + i * 1024);
      asm volatile("s_waitcnt vmcnt(0)" ::: "memory");
      __builtin_amdgcn_sched_barrier(0);
      unsigned ok = 1u;
#pragma unroll
      for (int i = 0; i < 8; ++i) {
        ok &= (unsigned)((sv[i].x >> 16) == exp);
        ok &= (unsigned)((sv[i].y >> 16) == exp);
        ok &= (unsigned)((sv[i].z >> 16) == exp);
        ok &= (unsigned)((sv[i].w >> 16) == exp);
      }
      if (__all((int)ok)) break;
      __builtin_amdgcn_s_sleep(1);
    }
#pragma unroll
    for (int i = 0; i < 8; ++i) {
      int idx = tid + i * 256;  // row = idx>>8 in [0,8), col4 = (idx&255)*4
      uint32_t p0 = (sv[i].x & 0xffffu) | (sv[i].y << 16);
      uint32_t p1 = (sv[i].z & 0xffffu) | (sv[i].w << 16);
      *(uint2*)&panel[idx >> 8][(idx & 255) * 4] = make_uint2(p0, p1);
    }
  };

  for (int t = 0; t < NT; ++t) {
    // (a) prefetch gate streams for this step (clamped rows for lane>=32)
    float xzv[4], xrv[4], xhv[4], gmv[4];
    {
      const int tg = (t + 1 < NT) ? t + 1 : t;
#pragma unroll
      for (int j = 0; j < 4; ++j) {
        int rr = erow + j; if (rr > 7) rr = 7;
        size_t base = (((size_t)(t * 64 + g * 8 + rr)) << 10) + ecol;
        if (w < 2) {
          xzv[j] = h2f(g_xz[base]);
          xhv[j] = h2f(g_xh[base]);
          gmv[j] = h2f(g_gamma[(((size_t)(tg * 64 + g * 8 + rr)) << 10) + ecol]);
          xrv[j] = 0.f;
        } else {
          xrv[j] = h2f(g_xr[base]);
          xzv[j] = xhv[j] = gmv[j] = 0.f;
        }
      }
    }

    // (b) poll h_dec(t) panel -> Hp
    poll_fill(Hbuf, (unsigned)t, Hp);
    __syncthreads();  // (c) Hp ready; red free

    // (d) P1 MFMA: z and r partials over K-slice
    f32x4 az0 = {0.f,0.f,0.f,0.f}, az1 = {0.f,0.f,0.f,0.f};
    f32x4 ar0 = {0.f,0.f,0.f,0.f}, ar1 = {0.f,0.f,0.f,0.f};
#pragma unroll
    for (int kc = 0; kc < 8; ++kc) {
      half8 av = *(const half8*)(aprow + aoff + kc * 32);
      az0 = __builtin_amdgcn_mfma_f32_16x16x32_f16(av, Bz[0][kc], az0, 0, 0, 0);
      az1 = __builtin_amdgcn_mfma_f32_16x16x32_f16(av, Bz[1][kc], az1, 0, 0, 0);
      ar0 = __builtin_amdgcn_mfma_f32_16x16x32_f16(av, Br[0][kc], ar0, 0, 0, 0);
      ar1 = __builtin_amdgcn_mfma_f32_16x16x32_f16(av, Br[1][kc], ar1, 0, 0, 0);
    }
    *(f32x4*)&red[w][0][lane * 4] = az0;
    *(f32x4*)&red[w][1][lane * 4] = az1;
    *(f32x4*)&red[w][2][lane * 4] = ar0;
    *(f32x4*)&red[w][3][lane * 4] = ar1;
    __syncthreads();

    // (e) reduce tile w; waves 0,1 keep z,hd; waves 2,3 stage RH into pub
    float zk[4] = {0.f,0.f,0.f,0.f}, hdk[4] = {0.f,0.f,0.f,0.f};
    {
      f32x4 s = *(const f32x4*)&red[0][w][lane * 4];
      s += *(const f32x4*)&red[1][w][lane * 4];
      s += *(const f32x4*)&red[2][w][lane * 4];
      s += *(const f32x4*)&red[3][w][lane * 4];
      if (lane < 32) {
        if (w < 2) {
#pragma unroll
          for (int j = 0; j < 4; ++j) {
            zk[j] = sigm(xzv[j] + s[j]);
            hdk[j] = h2f(Hp[erow + j][ecol]);
          }
        } else {
#pragma unroll
          for (int j = 0; j < 4; ++j) {
            float rg = sigm(xrv[j] + s[j]);
            float hd = h2f(Hp[erow + j][ecol]);
            pub[erow + j][ect * 16 + r16] =
                ((unsigned)(t + 1) << 16) | (uint32_t)f2h(rg * hd);
          }
        }
      }
    }
    __syncthreads();
    if (tid < 64) {
      int r = tid >> 3, cq = (tid & 7) * 4;
      st_cg_b128(RHbuf + (((size_t)(g * 8 + r)) << 10) + c0 + cq,
                 *(u32x4*)&pub[r][cq]);
    }

    // (f) poll RH(t) panel -> RHp
    poll_fill(RHbuf, (unsigned)(t + 1), RHp);
    __syncthreads();  // RHp ready; red consumed by all

    // (g) P2 MFMA: hprop partials
    f32x4 ah0 = {0.f,0.f,0.f,0.f}, ah1 = {0.f,0.f,0.f,0.f};
#pragma unroll
    for (int kc = 0; kc < 8; ++kc) {
      half8 av = *(const half8*)(aprow2 + aoff + kc * 32);
      ah0 = __builtin_amdgcn_mfma_f32_16x16x32_f16(av, Bh[0][kc], ah0, 0, 0, 0);
      ah1 = __builtin_amdgcn_mfma_f32_16x16x32_f16(av, Bh[1][kc], ah1, 0, 0, 0);
    }
    *(f32x4*)&red[w][0][lane * 4] = ah0;
    *(f32x4*)&red[w][1][lane * 4] = ah1;
    __syncthreads();

    // (h) reduce + combine + stage h_dec(t+1); waves 0,1
    if (w < 2) {
      f32x4 s = *(const f32x4*)&red[0][w][lane * 4];
      s += *(const f32x4*)&red[1][w][lane * 4];
      s += *(const f32x4*)&red[2][w][lane * 4];
      s += *(const f32x4*)&red[3][w][lane * 4];
      if (lane < 32) {
#pragma unroll
        for (int j = 0; j < 4; ++j) {
          float hp = fast_tanh(xhv[j] + s[j]);
          float h = (1.f - zk[j]) * hdk[j] + zk[j] * hp;
          int b = g * 8 + erow + j;
          out[((size_t)b * NT + t) * NH + ecol] = h;
          pub[erow + j][ect * 16 + r16] =
              ((unsigned)(t + 1) << 16) | (uint32_t)f2h(gmv[j] * h);
        }
      }
    }
    __syncthreads();
    if (t + 1 < NT && tid < 64) {
      int r = tid >> 3, cq = (tid & 7) * 4;
      st_cg_b128(Hbuf + (((size_t)(g * 8 + r)) << 10) + c0 + cq,
                 *(u32x4*)&pub[r][cq]);
    }
  }
}

// ---- launch ------------------------------------------------------------

extern "C" void kernel_launch(void* const* d_in, const int* in_sizes, int n_in,
                              void* d_out, int out_size, void* d_ws, size_t ws_size,
                              hipStream_t stream) {
  const float* x  = (const float*)d_in[0];
  const float* Wd = (const float*)d_in[1];
  const float* bd = (const float*)d_in[2];
  const float* Wz = (const float*)d_in[3];
  const float* Wr = (const float*)d_in[4];
  const float* Wh = (const float*)d_in[5];
  const float* Uz = (const float*)d_in[6];
  const float* Ur = (const float*)d_in[7];
  const float* Uh = (const float*)d_in[8];
  const float* bz = (const float*)d_in[9];
  const float* br = (const float*)d_in[10];
  const float* bh = (const float*)d_in[11];
  float* out = (float*)d_out;

  char* ws = (char*)d_ws;
  size_t off = 0;
  auto take = [&](size_t bytes) -> char* {
    char* p = ws + off;
    off = (off + bytes + 255) & ~(size_t)255;
    return p;
  };
  uint32_t* x2  = (uint32_t*)take((size_t)32768 * 128 * 4);    // 16 MiB
  uint32_t* W2  = (uint32_t*)take((size_t)4 * 128 * 1024 * 4); // 2 MiB
  uint16_t* UzT = (uint16_t*)take((size_t)1024 * 1024 * 2);    // 2 MiB
  uint16_t* UrT = (uint16_t*)take((size_t)1024 * 1024 * 2);
  uint16_t* UhT = (uint16_t*)take((size_t)1024 * 1024 * 2);
  uint16_t* g_gamma = (uint16_t*)take((size_t)NT * NB * NH * 2); // 64 MiB
  uint16_t* g_xz   = (uint16_t*)take((size_t)NT * NB * NH * 2);
  uint16_t* g_xr   = (uint16_t*)take((size_t)NT * NB * NH * 2);
  uint16_t* g_xh   = (uint16_t*)take((size_t)NT * NB * NH * 2);
  uint32_t* Hbuf   = (uint32_t*)take((size_t)NB * NH * 4);     // 256 KiB
  uint32_t* RHbuf  = (uint32_t*)take((size_t)NB * NH * 4);     // 256 KiB
  (void)ws_size; (void)in_sizes; (void)n_in; (void)out_size;

  (void)hipMemsetAsync(Hbuf, 0, (size_t)NB * NH * 4, stream);   // tag 0, h=0
  (void)hipMemsetAsync(RHbuf, 0, (size_t)NB * NH * 4, stream);  // tag 0

  pack_x_k<<<2048, 256, 0, stream>>>((const float2*)x, x2, 32768 * 128);
  pack_rows_k<<<512, 256, 0, stream>>>(Wd, W2 + 0 * (128 * 1024), ND);
  pack_rows_k<<<512, 256, 0, stream>>>(Wz, W2 + 1 * (128 * 1024), ND);
  pack_rows_k<<<512, 256, 0, stream>>>(Wr, W2 + 2 * (128 * 1024), ND);
  pack_rows_k<<<512, 256, 0, stream>>>(Wh, W2 + 3 * (128 * 1024), ND);
  transpose_f2h_k<<<256, 256, 0, stream>>>(Uz, UzT);
  transpose_f2h_k<<<256, 256, 0, stream>>>(Ur, UrT);
  transpose_f2h_k<<<256, 256, 0, stream>>>(Uh, UhT);

  proj_k<<<32768, 256, 0, stream>>>(x2, W2, bd, bz, br, bh,
                                    g_gamma, g_xz, g_xr, g_xh);

  scan_k<<<256, 256, 0, stream>>>(UzT, UrT, UhT, g_gamma, g_xz, g_xr, g_xh,
                                  Hbuf, RHbuf, out);
}

// Round 13
// 4395.502 us; speedup vs baseline: 1.0542x; 1.0542x over previous
//
#include <hip/hip_runtime.h>
#include <cstdint>
#include <cstddef>

// GRU-D: B=64, T=512, D=256, H=1024.
// v12 = v9 (proven, 3.81 ms scan) + ONE local change: non-temporal loads for
// the gate streams and non-temporal stores for `out`. These are touch-once
// streams (256 MB + 128 MB per iteration) that were thrashing L3 and evicting
// the 512 KB exchange buffers -> polls missed to DRAM. nt keeps the exchange
// MALL-resident. Sync/dataflow byte-identical to v9. (v11 probe reverted.)

#define NB 64
#define NT 512
#define ND 256
#define NH 1024

typedef _Float16 h2_t __attribute__((ext_vector_type(2)));
typedef _Float16 half8 __attribute__((ext_vector_type(8)));
typedef float f32x4 __attribute__((ext_vector_type(4)));
typedef uint32_t u32x4 __attribute__((ext_vector_type(4)));

__device__ __forceinline__ float fdot2(uint32_t a, uint32_t b, float acc) {
  h2_t ha = __builtin_bit_cast(h2_t, a);
  h2_t hb = __builtin_bit_cast(h2_t, b);
#if __has_builtin(__builtin_amdgcn_fdot2)
  return __builtin_amdgcn_fdot2(ha, hb, acc, false);
#else
  return acc + (float)ha[0] * (float)hb[0] + (float)ha[1] * (float)hb[1];
#endif
}

__device__ __forceinline__ uint32_t pack2(float a, float b) {
  h2_t v; v[0] = (_Float16)a; v[1] = (_Float16)b;
  return __builtin_bit_cast(uint32_t, v);
}
__device__ __forceinline__ uint16_t f2h(float x) {
  _Float16 v = (_Float16)x; return __builtin_bit_cast(uint16_t, v);
}
__device__ __forceinline__ float h2f(uint16_t u) {
  return (float)__builtin_bit_cast(_Float16, u);
}
__device__ __forceinline__ float sigm(float x) {
  return 1.f / (1.f + __expf(-x));
}
__device__ __forceinline__ float fast_tanh(float x) {
  float e = __expf(2.f * x);
  return 1.f - 2.f / (e + 1.f);
}
// non-temporal (stream-once) accessors
__device__ __forceinline__ float ldnt_h(const uint16_t* p) {
  return h2f(__builtin_nontemporal_load(p));
}
__device__ __forceinline__ void stnt_f(float* p, float v) {
  __builtin_nontemporal_store(v, p);
}

// device-coherent (bypass L1/L2, served at MALL)
__device__ __forceinline__ uint4 ld_cg_b128(const uint32_t* p) {
  uint4 v;
  asm volatile("global_load_dwordx4 %0, %1, off sc0 sc1" : "=v"(v) : "v"(p) : "memory");
  return v;
}
__device__ __forceinline__ void st_cg_b128(uint32_t* p, u32x4 v) {
  asm volatile("global_store_dwordx4 %0, %1, off sc0 sc1" :: "v"(p), "v"(v) : "memory");
}

// ---- pack kernels ------------------------------------------------------

__global__ void pack_x_k(const float2* __restrict__ x, uint32_t* __restrict__ x2, int n) {
  int stride = gridDim.x * blockDim.x;
  for (int i = blockIdx.x * blockDim.x + threadIdx.x; i < n; i += stride) {
    float2 v = x[i];
    x2[i] = pack2(v.x, v.y);
  }
}

// src [K][1024] f32 -> dst [K/2][1024] f16x2 (pairs along K) — for W
__global__ void pack_rows_k(const float* __restrict__ src, uint32_t* __restrict__ dst, int K) {
  int n = (K >> 1) * NH;
  int stride = gridDim.x * blockDim.x;
  for (int i = blockIdx.x * blockDim.x + threadIdx.x; i < n; i += stride) {
    int kp = i >> 10, j = i & 1023;
    dst[i] = pack2(src[(2 * kp) * NH + j], src[(2 * kp + 1) * NH + j]);
  }
}

// U [1024][1024] f32 -> UT [1024 cols][1024 k] f16. 64x64 LDS tiles.
__global__ __launch_bounds__(256) void transpose_f2h_k(
    const float* __restrict__ src, uint16_t* __restrict__ dst) {
  __shared__ uint16_t lt[64][68];
  int tr = blockIdx.x & 15, tc = blockIdx.x >> 4;
  int tid = threadIdx.x;
  int r0 = tid >> 6, cc = tid & 63;
#pragma unroll
  for (int it = 0; it < 16; ++it) {
    int r = it * 4 + r0;
    lt[cc][r] = f2h(src[(size_t)(tr * 64 + r) * 1024 + tc * 64 + cc]);
  }
  __syncthreads();
#pragma unroll
  for (int it = 0; it < 16; ++it) {
    int c = it * 4 + r0;
    dst[(size_t)(tc * 64 + c) * 1024 + tr * 64 + cc] = lt[c][cc];
  }
}

// ---- phase 1: input projections (proven) -------------------------------
__global__ __launch_bounds__(256) void proj_k(
    const uint32_t* __restrict__ x2, const uint32_t* __restrict__ W2,
    const float* __restrict__ bd, const float* __restrict__ bz,
    const float* __restrict__ br, const float* __restrict__ bh,
    uint16_t* __restrict__ g_gamma, uint16_t* __restrict__ g_xz,
    uint16_t* __restrict__ g_xr, uint16_t* __restrict__ g_xh) {
  __shared__ uint32_t xs[64 * 132];
  int wg = blockIdx.x;
  int rg = wg >> 6;
  int cg = wg & 63;
  int tid = threadIdx.x;

  const uint4* xsrc = (const uint4*)x2 + (size_t)rg * 64 * 32;
#pragma unroll
  for (int w = 0; w < 8; ++w) {
    int f = tid + w * 256;
    int row = f >> 5, q = f & 31;
    *(uint4*)&xs[row * 132 + q * 4] = xsrc[row * 32 + q];
  }
  __syncthreads();

  int a = cg >> 4;
  int j0 = (cg & 15) * 64 + (tid & 15) * 4;
  int tr = tid >> 4;
  const uint32_t* W2a = W2 + (size_t)a * (128 * 1024) + j0;

  float acc[4][4] = {};
#pragma unroll 4
  for (int kp = 0; kp < 128; ++kp) {
    uint32_t xv0 = xs[(tr * 4 + 0) * 132 + kp];
    uint32_t xv1 = xs[(tr * 4 + 1) * 132 + kp];
    uint32_t xv2 = xs[(tr * 4 + 2) * 132 + kp];
    uint32_t xv3 = xs[(tr * 4 + 3) * 132 + kp];
    uint4 wv = *(const uint4*)(W2a + (size_t)kp * 1024);
    acc[0][0] = fdot2(xv0, wv.x, acc[0][0]); acc[0][1] = fdot2(xv0, wv.y, acc[0][1]);
    acc[0][2] = fdot2(xv0, wv.z, acc[0][2]); acc[0][3] = fdot2(xv0, wv.w, acc[0][3]);
    acc[1][0] = fdot2(xv1, wv.x, acc[1][0]); acc[1][1] = fdot2(xv1, wv.y, acc[1][1]);
    acc[1][2] = fdot2(xv1, wv.z, acc[1][2]); acc[1][3] = fdot2(xv1, wv.w, acc[1][3]);
    acc[2][0] = fdot2(xv2, wv.x, acc[2][0]); acc[2][1] = fdot2(xv2, wv.y, acc[2][1]);
    acc[2][2] = fdot2(xv2, wv.z, acc[2][2]); acc[2][3] = fdot2(xv2, wv.w, acc[2][3]);
    acc[3][0] = fdot2(xv3, wv.x, acc[3][0]); acc[3][1] = fdot2(xv3, wv.y, acc[3][1]);
    acc[3][2] = fdot2(xv3, wv.z, acc[3][2]); acc[3][3] = fdot2(xv3, wv.w, acc[3][3]);
  }

  const float* bias = a == 0 ? bd : a == 1 ? bz : a == 2 ? br : bh;
  uint16_t* dst = a == 0 ? g_gamma : a == 1 ? g_xz : a == 2 ? g_xr : g_xh;
  float b0 = bias[j0], b1 = bias[j0 + 1], b2 = bias[j0 + 2], b3 = bias[j0 + 3];
#pragma unroll
  for (int i = 0; i < 4; ++i) {
    int n = rg * 64 + tr * 4 + i;
    int b = n >> 9, t = n & 511;
    float p0 = acc[i][0] + b0, p1 = acc[i][1] + b1;
    float p2 = acc[i][2] + b2, p3 = acc[i][3] + b3;
    if (a == 0) {
      p0 = __expf(-fmaxf(p0, 0.f)); p1 = __expf(-fmaxf(p1, 0.f));
      p2 = __expf(-fmaxf(p2, 0.f)); p3 = __expf(-fmaxf(p3, 0.f));
    }
    uint32_t* o = (uint32_t*)(dst + (((size_t)(t * 64 + b)) << 10) + j0);
    o[0] = pack2(p0, p1);
    o[1] = pack2(p2, p3);
  }
}

// ---- v12 scan (= v9 + nt gate loads / nt out stores) -------------------

__global__ __launch_bounds__(256, 1) void scan_k(
    const uint16_t* __restrict__ UzT, const uint16_t* __restrict__ UrT,
    const uint16_t* __restrict__ UhT,
    const uint16_t* __restrict__ g_gamma, const uint16_t* __restrict__ g_xz,
    const uint16_t* __restrict__ g_xr, const uint16_t* __restrict__ g_xh,
    uint32_t* __restrict__ Hbuf, uint32_t* __restrict__ RHbuf,
    float* __restrict__ out) {
  __shared__ uint16_t Hp[9][1032];   // h_dec panel rows 0-7, row 8 = zeros
  __shared__ uint16_t RHp[9][1032];
  __shared__ float red[4][4][256];
  __shared__ uint32_t pub[8][32];    // tagged publish staging

  const int tid = threadIdx.x;
  const int g = blockIdx.x & 7;
  const int slot = blockIdx.x >> 3;
  const int c0 = slot * 32;
  const int lane = tid & 63, w = tid >> 6;
  const int r16 = lane & 15, q = lane >> 4;

  for (int i = tid; i < 1032; i += 256) { Hp[8][i] = 0; RHp[8][i] = 0; }

  // ---- one-time: B fragments into registers (per wave: K in [w*256,+256))
  half8 Bz[2][8], Br[2][8], Bh[2][8];
#pragma unroll
  for (int ct = 0; ct < 2; ++ct) {
    const size_t colb = (size_t)(c0 + ct * 16 + r16) * 1024 + w * 256 + q * 8;
#pragma unroll
    for (int kc = 0; kc < 8; ++kc) {
      Bz[ct][kc] = *(const half8*)(UzT + colb + kc * 32);
      Br[ct][kc] = *(const half8*)(UrT + colb + kc * 32);
      Bh[ct][kc] = *(const half8*)(UhT + colb + kc * 32);
    }
  }
  __syncthreads();

  const uint16_t* aprow = Hp[r16 < 8 ? r16 : 8];
  const uint16_t* aprow2 = RHp[r16 < 8 ? r16 : 8];
  const int aoff = w * 256 + q * 8;

  // epilogue geometry: wave ct = w&1; rows erow..erow+3 (valid when lane<32)
  const int ect = w & 1;
  const int ecol = c0 + ect * 16 + r16;
  const int erow = q * 4;

  auto poll_fill = [&](const uint32_t* __restrict__ buf, unsigned exp,
                       uint16_t (&panel)[9][1032]) {
    const uint32_t* base = buf + ((size_t)g << 13) + (size_t)tid * 4;
    uint4 sv[8];
    for (;;) {
#pragma unroll
      for (int i = 0; i < 8; ++i) sv[i] = ld_cg_b128(base + i * 1024);
      asm volatile("s_waitcnt vmcnt(0)" ::: "memory");
      __builtin_amdgcn_sched_barrier(0);
      unsigned ok = 1u;
#pragma unroll
      for (int i = 0; i < 8; ++i) {
        ok &= (unsigned)((sv[i].x >> 16) == exp);
        ok &= (unsigned)((sv[i].y >> 16) == exp);
        ok &= (unsigned)((sv[i].z >> 16) == exp);
        ok &= (unsigned)((sv[i].w >> 16) == exp);
      }
      if (__all((int)ok)) break;
      __builtin_amdgcn_s_sleep(1);
    }
#pragma unroll
    for (int i = 0; i < 8; ++i) {
      int idx = tid + i * 256;  // row = idx>>8 in [0,8), col4 = (idx&255)*4
      uint32_t p0 = (sv[i].x & 0xffffu) | (sv[i].y << 16);
      uint32_t p1 = (sv[i].z & 0xffffu) | (sv[i].w << 16);
      *(uint2*)&panel[idx >> 8][(idx & 255) * 4] = make_uint2(p0, p1);
    }
  };

  for (int t = 0; t < NT; ++t) {
    // (a) prefetch gate streams (non-temporal; clamped rows for lane>=32)
    float xzv[4], xrv[4], xhv[4], gmv[4];
    {
      const int tg = (t + 1 < NT) ? t + 1 : t;
#pragma unroll
      for (int j = 0; j < 4; ++j) {
        int rr = erow + j; if (rr > 7) rr = 7;
        size_t base = (((size_t)(t * 64 + g * 8 + rr)) << 10) + ecol;
        if (w < 2) {
          xzv[j] = ldnt_h(&g_xz[base]);
          xhv[j] = ldnt_h(&g_xh[base]);
          gmv[j] = ldnt_h(&g_gamma[(((size_t)(tg * 64 + g * 8 + rr)) << 10) + ecol]);
          xrv[j] = 0.f;
        } else {
          xrv[j] = ldnt_h(&g_xr[base]);
          xzv[j] = xhv[j] = gmv[j] = 0.f;
        }
      }
    }

    // (b) poll h_dec(t) panel -> Hp
    poll_fill(Hbuf, (unsigned)t, Hp);
    __syncthreads();  // (c) Hp ready; red free

    // (d) P1 MFMA: z and r partials over K-slice
    f32x4 az0 = {0.f,0.f,0.f,0.f}, az1 = {0.f,0.f,0.f,0.f};
    f32x4 ar0 = {0.f,0.f,0.f,0.f}, ar1 = {0.f,0.f,0.f,0.f};
#pragma unroll
    for (int kc = 0; kc < 8; ++kc) {
      half8 av = *(const half8*)(aprow + aoff + kc * 32);
      az0 = __builtin_amdgcn_mfma_f32_16x16x32_f16(av, Bz[0][kc], az0, 0, 0, 0);
      az1 = __builtin_amdgcn_mfma_f32_16x16x32_f16(av, Bz[1][kc], az1, 0, 0, 0);
      ar0 = __builtin_amdgcn_mfma_f32_16x16x32_f16(av, Br[0][kc], ar0, 0, 0, 0);
      ar1 = __builtin_amdgcn_mfma_f32_16x16x32_f16(av, Br[1][kc], ar1, 0, 0, 0);
    }
    *(f32x4*)&red[w][0][lane * 4] = az0;
    *(f32x4*)&red[w][1][lane * 4] = az1;
    *(f32x4*)&red[w][2][lane * 4] = ar0;
    *(f32x4*)&red[w][3][lane * 4] = ar1;
    __syncthreads();

    // (e) reduce tile w; waves 0,1 keep z,hd; waves 2,3 stage RH into pub
    float zk[4] = {0.f,0.f,0.f,0.f}, hdk[4] = {0.f,0.f,0.f,0.f};
    {
      f32x4 s = *(const f32x4*)&red[0][w][lane * 4];
      s += *(const f32x4*)&red[1][w][lane * 4];
      s += *(const f32x4*)&red[2][w][lane * 4];
      s += *(const f32x4*)&red[3][w][lane * 4];
      if (lane < 32) {
        if (w < 2) {
#pragma unroll
          for (int j = 0; j < 4; ++j) {
            zk[j] = sigm(xzv[j] + s[j]);
            hdk[j] = h2f(Hp[erow + j][ecol]);
          }
        } else {
#pragma unroll
          for (int j = 0; j < 4; ++j) {
            float rg = sigm(xrv[j] + s[j]);
            float hd = h2f(Hp[erow + j][ecol]);
            pub[erow + j][ect * 16 + r16] =
                ((unsigned)(t + 1) << 16) | (uint32_t)f2h(rg * hd);
          }
        }
      }
    }
    __syncthreads();
    if (tid < 64) {
      int r = tid >> 3, cq = (tid & 7) * 4;
      st_cg_b128(RHbuf + (((size_t)(g * 8 + r)) << 10) + c0 + cq,
                 *(u32x4*)&pub[r][cq]);
    }

    // (f) poll RH(t) panel -> RHp
    poll_fill(RHbuf, (unsigned)(t + 1), RHp);
    __syncthreads();  // RHp ready; red consumed by all

    // (g) P2 MFMA: hprop partials
    f32x4 ah0 = {0.f,0.f,0.f,0.f}, ah1 = {0.f,0.f,0.f,0.f};
#pragma unroll
    for (int kc = 0; kc < 8; ++kc) {
      half8 av = *(const half8*)(aprow2 + aoff + kc * 32);
      ah0 = __builtin_amdgcn_mfma_f32_16x16x32_f16(av, Bh[0][kc], ah0, 0, 0, 0);
      ah1 = __builtin_amdgcn_mfma_f32_16x16x32_f16(av, Bh[1][kc], ah1, 0, 0, 0);
    }
    *(f32x4*)&red[w][0][lane * 4] = ah0;
    *(f32x4*)&red[w][1][lane * 4] = ah1;
    __syncthreads();

    // (h) reduce + combine + stage h_dec(t+1); waves 0,1
    if (w < 2) {
      f32x4 s = *(const f32x4*)&red[0][w][lane * 4];
      s += *(const f32x4*)&red[1][w][lane * 4];
      s += *(const f32x4*)&red[2][w][lane * 4];
      s += *(const f32x4*)&red[3][w][lane * 4];
      if (lane < 32) {
#pragma unroll
        for (int j = 0; j < 4; ++j) {
          float hp = fast_tanh(xhv[j] + s[j]);
          float h = (1.f - zk[j]) * hdk[j] + zk[j] * hp;
          int b = g * 8 + erow + j;
          stnt_f(&out[((size_t)b * NT + t) * NH + ecol], h);
          pub[erow + j][ect * 16 + r16] =
              ((unsigned)(t + 1) << 16) | (uint32_t)f2h(gmv[j] * h);
        }
      }
    }
    __syncthreads();
    if (t + 1 < NT && tid < 64) {
      int r = tid >> 3, cq = (tid & 7) * 4;
      st_cg_b128(Hbuf + (((size_t)(g * 8 + r)) << 10) + c0 + cq,
                 *(u32x4*)&pub[r][cq]);
    }
  }
}

// ---- launch ------------------------------------------------------------

extern "C" void kernel_launch(void* const* d_in, const int* in_sizes, int n_in,
                              void* d_out, int out_size, void* d_ws, size_t ws_size,
                              hipStream_t stream) {
  const float* x  = (const float*)d_in[0];
  const float* Wd = (const float*)d_in[1];
  const float* bd = (const float*)d_in[2];
  const float* Wz = (const float*)d_in[3];
  const float* Wr = (const float*)d_in[4];
  const float* Wh = (const float*)d_in[5];
  const float* Uz = (const float*)d_in[6];
  const float* Ur = (const float*)d_in[7];
  const float* Uh = (const float*)d_in[8];
  const float* bz = (const float*)d_in[9];
  const float* br = (const float*)d_in[10];
  const float* bh = (const float*)d_in[11];
  float* out = (float*)d_out;

  char* ws = (char*)d_ws;
  size_t off = 0;
  auto take = [&](size_t bytes) -> char* {
    char* p = ws + off;
    off = (off + bytes + 255) & ~(size_t)255;
    return p;
  };
  uint32_t* x2  = (uint32_t*)take((size_t)32768 * 128 * 4);    // 16 MiB
  uint32_t* W2  = (uint32_t*)take((size_t)4 * 128 * 1024 * 4); // 2 MiB
  uint16_t* UzT = (uint16_t*)take((size_t)1024 * 1024 * 2);    // 2 MiB
  uint16_t* UrT = (uint16_t*)take((size_t)1024 * 1024 * 2);
  uint16_t* UhT = (uint16_t*)take((size_t)1024 * 1024 * 2);
  uint16_t* g_gamma = (uint16_t*)take((size_t)NT * NB * NH * 2); // 64 MiB
  uint16_t* g_xz   = (uint16_t*)take((size_t)NT * NB * NH * 2);
  uint16_t* g_xr   = (uint16_t*)take((size_t)NT * NB * NH * 2);
  uint16_t* g_xh   = (uint16_t*)take((size_t)NT * NB * NH * 2);
  uint32_t* Hbuf   = (uint32_t*)take((size_t)NB * NH * 4);     // 256 KiB
  uint32_t* RHbuf  = (uint32_t*)take((size_t)NB * NH * 4);     // 256 KiB
  (void)ws_size; (void)in_sizes; (void)n_in; (void)out_size;

  (void)hipMemsetAsync(Hbuf, 0, (size_t)NB * NH * 4, stream);   // tag 0, h=0
  (void)hipMemsetAsync(RHbuf, 0, (size_t)NB * NH * 4, stream);  // tag 0

  pack_x_k<<<2048, 256, 0, stream>>>((const float2*)x, x2, 32768 * 128);
  pack_rows_k<<<512, 256, 0, stream>>>(Wd, W2 + 0 * (128 * 1024), ND);
  pack_rows_k<<<512, 256, 0, stream>>>(Wz, W2 + 1 * (128 * 1024), ND);
  pack_rows_k<<<512, 256, 0, stream>>>(Wr, W2 + 2 * (128 * 1024), ND);
  pack_rows_k<<<512, 256, 0, stream>>>(Wh, W2 + 3 * (128 * 1024), ND);
  transpose_f2h_k<<<256, 256, 0, stream>>>(Uz, UzT);
  transpose_f2h_k<<<256, 256, 0, stream>>>(Ur, UrT);
  transpose_f2h_k<<<256, 256, 0, stream>>>(Uh, UhT);

  proj_k<<<32768, 256, 0, stream>>>(x2, W2, bd, bz, br, bh,
                                    g_gamma, g_xz, g_xr, g_xh);

  scan_k<<<256, 256, 0, stream>>>(UzT, UrT, UhT, g_gamma, g_xz, g_xr, g_xh,
                                  Hbuf, RHbuf, out);
}

// Round 14
// 3702.419 us; speedup vs baseline: 1.2516x; 1.1872x over previous
//
#include <hip/hip_runtime.h>
#include <cstdint>
#include <cstddef>

// GRU-D: B=64, T=512, D=256, H=1024.
// v13 = v12 with the exchange rebuilt as ack-ordered release:
//  - data buffers are pure f16 (16 KB/group panel, half of v9's tagged u32)
//  - per-producer tag dwords, stored AFTER s_waitcnt vmcnt(0) acks the data
//    (sc1 store-ack = globally visible at PoC), so tag==t implies data ready
//  - consumer: cheap tag spin (32 dwords) then ONE unverified 16 KB read
// Sync topology / grouping / MFMA pipeline identical to v9/v12 (proven).

#define NB 64
#define NT 512
#define ND 256
#define NH 1024

typedef _Float16 h2_t __attribute__((ext_vector_type(2)));
typedef _Float16 half8 __attribute__((ext_vector_type(8)));
typedef float f32x4 __attribute__((ext_vector_type(4)));
typedef uint32_t u32x4 __attribute__((ext_vector_type(4)));

__device__ __forceinline__ float fdot2(uint32_t a, uint32_t b, float acc) {
  h2_t ha = __builtin_bit_cast(h2_t, a);
  h2_t hb = __builtin_bit_cast(h2_t, b);
#if __has_builtin(__builtin_amdgcn_fdot2)
  return __builtin_amdgcn_fdot2(ha, hb, acc, false);
#else
  return acc + (float)ha[0] * (float)hb[0] + (float)ha[1] * (float)hb[1];
#endif
}

__device__ __forceinline__ uint32_t pack2(float a, float b) {
  h2_t v; v[0] = (_Float16)a; v[1] = (_Float16)b;
  return __builtin_bit_cast(uint32_t, v);
}
__device__ __forceinline__ uint16_t f2h(float x) {
  _Float16 v = (_Float16)x; return __builtin_bit_cast(uint16_t, v);
}
__device__ __forceinline__ float h2f(uint16_t u) {
  return (float)__builtin_bit_cast(_Float16, u);
}
__device__ __forceinline__ float sigm(float x) {
  return 1.f / (1.f + __expf(-x));
}
__device__ __forceinline__ float fast_tanh(float x) {
  float e = __expf(2.f * x);
  return 1.f - 2.f / (e + 1.f);
}
__device__ __forceinline__ float ldnt_h(const uint16_t* p) {
  return h2f(__builtin_nontemporal_load(p));
}
__device__ __forceinline__ void stnt_f(float* p, float v) {
  __builtin_nontemporal_store(v, p);
}

// device-coherent (bypass L1/L2, served at MALL)
__device__ __forceinline__ u32x4 ld_cg_b128(const uint32_t* p) {
  u32x4 v;
  asm volatile("global_load_dwordx4 %0, %1, off sc0 sc1" : "=v"(v) : "v"(p) : "memory");
  return v;
}
__device__ __forceinline__ void st_cg_b128(uint32_t* p, u32x4 v) {
  asm volatile("global_store_dwordx4 %0, %1, off sc0 sc1" :: "v"(p), "v"(v) : "memory");
}
__device__ __forceinline__ void st_cg_b32(uint32_t* p, unsigned v) {
  asm volatile("global_store_dword %0, %1, off sc0 sc1" :: "v"(p), "v"(v) : "memory");
}
__device__ __forceinline__ unsigned ld_cg_b32w(const uint32_t* p) {
  unsigned v;
  asm volatile("global_load_dword %0, %1, off sc0 sc1\n\ts_waitcnt vmcnt(0)"
               : "=v"(v) : "v"(p) : "memory");
  return v;
}

// ---- pack kernels ------------------------------------------------------

__global__ void pack_x_k(const float2* __restrict__ x, uint32_t* __restrict__ x2, int n) {
  int stride = gridDim.x * blockDim.x;
  for (int i = blockIdx.x * blockDim.x + threadIdx.x; i < n; i += stride) {
    float2 v = x[i];
    x2[i] = pack2(v.x, v.y);
  }
}

// src [K][1024] f32 -> dst [K/2][1024] f16x2 (pairs along K) — for W
__global__ void pack_rows_k(const float* __restrict__ src, uint32_t* __restrict__ dst, int K) {
  int n = (K >> 1) * NH;
  int stride = gridDim.x * blockDim.x;
  for (int i = blockIdx.x * blockDim.x + threadIdx.x; i < n; i += stride) {
    int kp = i >> 10, j = i & 1023;
    dst[i] = pack2(src[(2 * kp) * NH + j], src[(2 * kp + 1) * NH + j]);
  }
}

// U [1024][1024] f32 -> UT [1024 cols][1024 k] f16. 64x64 LDS tiles.
__global__ __launch_bounds__(256) void transpose_f2h_k(
    const float* __restrict__ src, uint16_t* __restrict__ dst) {
  __shared__ uint16_t lt[64][68];
  int tr = blockIdx.x & 15, tc = blockIdx.x >> 4;
  int tid = threadIdx.x;
  int r0 = tid >> 6, cc = tid & 63;
#pragma unroll
  for (int it = 0; it < 16; ++it) {
    int r = it * 4 + r0;
    lt[cc][r] = f2h(src[(size_t)(tr * 64 + r) * 1024 + tc * 64 + cc]);
  }
  __syncthreads();
#pragma unroll
  for (int it = 0; it < 16; ++it) {
    int c = it * 4 + r0;
    dst[(size_t)(tc * 64 + c) * 1024 + tr * 64 + cc] = lt[c][cc];
  }
}

// ---- phase 1: input projections (proven) -------------------------------
__global__ __launch_bounds__(256) void proj_k(
    const uint32_t* __restrict__ x2, const uint32_t* __restrict__ W2,
    const float* __restrict__ bd, const float* __restrict__ bz,
    const float* __restrict__ br, const float* __restrict__ bh,
    uint16_t* __restrict__ g_gamma, uint16_t* __restrict__ g_xz,
    uint16_t* __restrict__ g_xr, uint16_t* __restrict__ g_xh) {
  __shared__ uint32_t xs[64 * 132];
  int wg = blockIdx.x;
  int rg = wg >> 6;
  int cg = wg & 63;
  int tid = threadIdx.x;

  const uint4* xsrc = (const uint4*)x2 + (size_t)rg * 64 * 32;
#pragma unroll
  for (int w = 0; w < 8; ++w) {
    int f = tid + w * 256;
    int row = f >> 5, q = f & 31;
    *(uint4*)&xs[row * 132 + q * 4] = xsrc[row * 32 + q];
  }
  __syncthreads();

  int a = cg >> 4;
  int j0 = (cg & 15) * 64 + (tid & 15) * 4;
  int tr = tid >> 4;
  const uint32_t* W2a = W2 + (size_t)a * (128 * 1024) + j0;

  float acc[4][4] = {};
#pragma unroll 4
  for (int kp = 0; kp < 128; ++kp) {
    uint32_t xv0 = xs[(tr * 4 + 0) * 132 + kp];
    uint32_t xv1 = xs[(tr * 4 + 1) * 132 + kp];
    uint32_t xv2 = xs[(tr * 4 + 2) * 132 + kp];
    uint32_t xv3 = xs[(tr * 4 + 3) * 132 + kp];
    uint4 wv = *(const uint4*)(W2a + (size_t)kp * 1024);
    acc[0][0] = fdot2(xv0, wv.x, acc[0][0]); acc[0][1] = fdot2(xv0, wv.y, acc[0][1]);
    acc[0][2] = fdot2(xv0, wv.z, acc[0][2]); acc[0][3] = fdot2(xv0, wv.w, acc[0][3]);
    acc[1][0] = fdot2(xv1, wv.x, acc[1][0]); acc[1][1] = fdot2(xv1, wv.y, acc[1][1]);
    acc[1][2] = fdot2(xv1, wv.z, acc[1][2]); acc[1][3] = fdot2(xv1, wv.w, acc[1][3]);
    acc[2][0] = fdot2(xv2, wv.x, acc[2][0]); acc[2][1] = fdot2(xv2, wv.y, acc[2][1]);
    acc[2][2] = fdot2(xv2, wv.z, acc[2][2]); acc[2][3] = fdot2(xv2, wv.w, acc[2][3]);
    acc[3][0] = fdot2(xv3, wv.x, acc[3][0]); acc[3][1] = fdot2(xv3, wv.y, acc[3][1]);
    acc[3][2] = fdot2(xv3, wv.z, acc[3][2]); acc[3][3] = fdot2(xv3, wv.w, acc[3][3]);
  }

  const float* bias = a == 0 ? bd : a == 1 ? bz : a == 2 ? br : bh;
  uint16_t* dst = a == 0 ? g_gamma : a == 1 ? g_xz : a == 2 ? g_xr : g_xh;
  float b0 = bias[j0], b1 = bias[j0 + 1], b2 = bias[j0 + 2], b3 = bias[j0 + 3];
#pragma unroll
  for (int i = 0; i < 4; ++i) {
    int n = rg * 64 + tr * 4 + i;
    int b = n >> 9, t = n & 511;
    float p0 = acc[i][0] + b0, p1 = acc[i][1] + b1;
    float p2 = acc[i][2] + b2, p3 = acc[i][3] + b3;
    if (a == 0) {
      p0 = __expf(-fmaxf(p0, 0.f)); p1 = __expf(-fmaxf(p1, 0.f));
      p2 = __expf(-fmaxf(p2, 0.f)); p3 = __expf(-fmaxf(p3, 0.f));
    }
    uint32_t* o = (uint32_t*)(dst + (((size_t)(t * 64 + b)) << 10) + j0);
    o[0] = pack2(p0, p1);
    o[1] = pack2(p2, p3);
  }
}

// ---- v13 scan (ack-ordered release exchange) ---------------------------

__global__ __launch_bounds__(256, 1) void scan_k(
    const uint16_t* __restrict__ UzT, const uint16_t* __restrict__ UrT,
    const uint16_t* __restrict__ UhT,
    const uint16_t* __restrict__ g_gamma, const uint16_t* __restrict__ g_xz,
    const uint16_t* __restrict__ g_xr, const uint16_t* __restrict__ g_xh,
    uint16_t* __restrict__ Hdat, uint16_t* __restrict__ RHdat,
    uint32_t* __restrict__ Htag, uint32_t* __restrict__ RHtag,
    float* __restrict__ out) {
  __shared__ __align__(16) uint16_t Hp[9][1032];   // rows 0-7, row 8 = zeros
  __shared__ __align__(16) uint16_t RHp[9][1032];
  __shared__ float red[4][4][256];
  __shared__ __align__(16) uint16_t pub16[8][32];  // own-block publish staging

  const int tid = threadIdx.x;
  const int g = blockIdx.x & 7;
  const int slot = blockIdx.x >> 3;
  const int c0 = slot * 32;
  const int lane = tid & 63, w = tid >> 6;
  const int r16 = lane & 15, q = lane >> 4;

  for (int i = tid; i < 1032; i += 256) { Hp[8][i] = 0; RHp[8][i] = 0; }

  // ---- one-time: B fragments (per wave: K in [w*256,+256))
  half8 Bz[2][8], Br[2][8], Bh[2][8];
#pragma unroll
  for (int ct = 0; ct < 2; ++ct) {
    const size_t colb = (size_t)(c0 + ct * 16 + r16) * 1024 + w * 256 + q * 8;
#pragma unroll
    for (int kc = 0; kc < 8; ++kc) {
      Bz[ct][kc] = *(const half8*)(UzT + colb + kc * 32);
      Br[ct][kc] = *(const half8*)(UrT + colb + kc * 32);
      Bh[ct][kc] = *(const half8*)(UhT + colb + kc * 32);
    }
  }
  __syncthreads();

  const uint16_t* aprow = Hp[r16 < 8 ? r16 : 8];
  const uint16_t* aprow2 = RHp[r16 < 8 ? r16 : 8];
  const int aoff = w * 256 + q * 8;

  // epilogue geometry: wave ct = w&1; rows erow..erow+3 (valid when lane<32)
  const int ect = w & 1;
  const int ecol = c0 + ect * 16 + r16;
  const int erow = q * 4;

  // tag slots: (group, producer slot) * 16 dwords (64B stride)
  uint32_t* mytagH = Htag + (g * 32 + slot) * 16;
  uint32_t* mytagR = RHtag + (g * 32 + slot) * 16;
  const uint32_t* tagH = Htag + (g * 32 + (tid & 31)) * 16;
  const uint32_t* tagR = RHtag + (g * 32 + (tid & 31)) * 16;

  // tag spin: every thread watches producer (tid&31); each wave covers all 32
  auto poll_tags = [&](const uint32_t* tp, unsigned exp) {
    for (;;) {
      unsigned v = ld_cg_b32w(tp);
      __builtin_amdgcn_sched_barrier(0);
      if (__all((int)(v == exp))) break;
      __builtin_amdgcn_s_sleep(2);
    }
  };
  // one unverified 16 KB panel read: thread -> row tid>>5, 64B chunk tid&31
  auto fill = [&](const uint16_t* dat, uint16_t (&panel)[9][1032]) {
    const uint32_t* src = (const uint32_t*)(dat +
        ((size_t)(g * 8 + (tid >> 5)) << 10) + (size_t)(tid & 31) * 32);
    u32x4 v0 = ld_cg_b128(src);
    u32x4 v1 = ld_cg_b128(src + 4);
    u32x4 v2 = ld_cg_b128(src + 8);
    u32x4 v3 = ld_cg_b128(src + 12);
    asm volatile("s_waitcnt vmcnt(0)" ::: "memory");
    __builtin_amdgcn_sched_barrier(0);
    uint16_t* dst = &panel[tid >> 5][(tid & 31) * 32];
    *(u32x4*)(dst + 0)  = v0;
    *(u32x4*)(dst + 8)  = v1;
    *(u32x4*)(dst + 16) = v2;
    *(u32x4*)(dst + 24) = v3;
  };
  // publish own 8x32 f16 block + ack + tag
  auto publish = [&](uint16_t* dat, uint32_t* tagp, unsigned tagval) {
    if (tid < 32) {
      int r = tid >> 2;            // 0..7
      int cq = (tid & 3) * 8;      // u16 offset within own 32 cols
      uint32_t* dp = (uint32_t*)(dat + ((size_t)(g * 8 + r) << 10) + c0 + cq);
      st_cg_b128(dp, *(u32x4*)&pub16[r][cq]);
      asm volatile("s_waitcnt vmcnt(0)" ::: "memory");  // data acked at PoC
      if (tid == 0) st_cg_b32(tagp, tagval);            // then release tag
    }
  };

  for (int t = 0; t < NT; ++t) {
    // (a) prefetch gate streams (non-temporal; clamped rows for lane>=32)
    float xzv[4], xrv[4], xhv[4], gmv[4];
    {
      const int tg = (t + 1 < NT) ? t + 1 : t;
#pragma unroll
      for (int j = 0; j < 4; ++j) {
        int rr = erow + j; if (rr > 7) rr = 7;
        size_t base = (((size_t)(t * 64 + g * 8 + rr)) << 10) + ecol;
        if (w < 2) {
          xzv[j] = ldnt_h(&g_xz[base]);
          xhv[j] = ldnt_h(&g_xh[base]);
          gmv[j] = ldnt_h(&g_gamma[(((size_t)(tg * 64 + g * 8 + rr)) << 10) + ecol]);
          xrv[j] = 0.f;
        } else {
          xrv[j] = ldnt_h(&g_xr[base]);
          xzv[j] = xhv[j] = gmv[j] = 0.f;
        }
      }
    }

    // (b) wait for h_dec(t): tag spin then single panel read
    poll_tags(tagH, (unsigned)t);
    fill(Hdat, Hp);
    __syncthreads();  // (c) Hp ready; red free

    // (d) P1 MFMA: z and r partials over K-slice
    f32x4 az0 = {0.f,0.f,0.f,0.f}, az1 = {0.f,0.f,0.f,0.f};
    f32x4 ar0 = {0.f,0.f,0.f,0.f}, ar1 = {0.f,0.f,0.f,0.f};
#pragma unroll
    for (int kc = 0; kc < 8; ++kc) {
      half8 av = *(const half8*)(aprow + aoff + kc * 32);
      az0 = __builtin_amdgcn_mfma_f32_16x16x32_f16(av, Bz[0][kc], az0, 0, 0, 0);
      az1 = __builtin_amdgcn_mfma_f32_16x16x32_f16(av, Bz[1][kc], az1, 0, 0, 0);
      ar0 = __builtin_amdgcn_mfma_f32_16x16x32_f16(av, Br[0][kc], ar0, 0, 0, 0);
      ar1 = __builtin_amdgcn_mfma_f32_16x16x32_f16(av, Br[1][kc], ar1, 0, 0, 0);
    }
    *(f32x4*)&red[w][0][lane * 4] = az0;
    *(f32x4*)&red[w][1][lane * 4] = az1;
    *(f32x4*)&red[w][2][lane * 4] = ar0;
    *(f32x4*)&red[w][3][lane * 4] = ar1;
    __syncthreads();

    // (e) reduce tile w; waves 0,1 keep z,hd; waves 2,3 stage RH into pub16
    float zk[4] = {0.f,0.f,0.f,0.f}, hdk[4] = {0.f,0.f,0.f,0.f};
    {
      f32x4 s = *(const f32x4*)&red[0][w][lane * 4];
      s += *(const f32x4*)&red[1][w][lane * 4];
      s += *(const f32x4*)&red[2][w][lane * 4];
      s += *(const f32x4*)&red[3][w][lane * 4];
      if (lane < 32) {
        if (w < 2) {
#pragma unroll
          for (int j = 0; j < 4; ++j) {
            zk[j] = sigm(xzv[j] + s[j]);
            hdk[j] = h2f(Hp[erow + j][ecol]);
          }
        } else {
#pragma unroll
          for (int j = 0; j < 4; ++j) {
            float rg = sigm(xrv[j] + s[j]);
            float hd = h2f(Hp[erow + j][ecol]);
            pub16[erow + j][ect * 16 + r16] = f2h(rg * hd);
          }
        }
      }
    }
    __syncthreads();
    publish(RHdat, mytagR, (unsigned)(t + 1));

    // (f) wait for RH(t)
    poll_tags(tagR, (unsigned)(t + 1));
    fill(RHdat, RHp);
    __syncthreads();  // RHp ready; red consumed by all

    // (g) P2 MFMA: hprop partials
    f32x4 ah0 = {0.f,0.f,0.f,0.f}, ah1 = {0.f,0.f,0.f,0.f};
#pragma unroll
    for (int kc = 0; kc < 8; ++kc) {
      half8 av = *(const half8*)(aprow2 + aoff + kc * 32);
      ah0 = __builtin_amdgcn_mfma_f32_16x16x32_f16(av, Bh[0][kc], ah0, 0, 0, 0);
      ah1 = __builtin_amdgcn_mfma_f32_16x16x32_f16(av, Bh[1][kc], ah1, 0, 0, 0);
    }
    *(f32x4*)&red[w][0][lane * 4] = ah0;
    *(f32x4*)&red[w][1][lane * 4] = ah1;
    __syncthreads();

    // (h) reduce + combine + stage h_dec(t+1) into pub16; waves 0,1
    if (w < 2) {
      f32x4 s = *(const f32x4*)&red[0][w][lane * 4];
      s += *(const f32x4*)&red[1][w][lane * 4];
      s += *(const f32x4*)&red[2][w][lane * 4];
      s += *(const f32x4*)&red[3][w][lane * 4];
      if (lane < 32) {
#pragma unroll
        for (int j = 0; j < 4; ++j) {
          float hp = fast_tanh(xhv[j] + s[j]);
          float h = (1.f - zk[j]) * hdk[j] + zk[j] * hp;
          int b = g * 8 + erow + j;
          stnt_f(&out[((size_t)b * NT + t) * NH + ecol], h);
          pub16[erow + j][ect * 16 + r16] = f2h(gmv[j] * h);
        }
      }
    }
    __syncthreads();
    if (t + 1 < NT) publish(Hdat, mytagH, (unsigned)(t + 1));
  }
}

// ---- launch ------------------------------------------------------------

extern "C" void kernel_launch(void* const* d_in, const int* in_sizes, int n_in,
                              void* d_out, int out_size, void* d_ws, size_t ws_size,
                              hipStream_t stream) {
  const float* x  = (const float*)d_in[0];
  const float* Wd = (const float*)d_in[1];
  const float* bd = (const float*)d_in[2];
  const float* Wz = (const float*)d_in[3];
  const float* Wr = (const float*)d_in[4];
  const float* Wh = (const float*)d_in[5];
  const float* Uz = (const float*)d_in[6];
  const float* Ur = (const float*)d_in[7];
  const float* Uh = (const float*)d_in[8];
  const float* bz = (const float*)d_in[9];
  const float* br = (const float*)d_in[10];
  const float* bh = (const float*)d_in[11];
  float* out = (float*)d_out;

  char* ws = (char*)d_ws;
  size_t off = 0;
  auto take = [&](size_t bytes) -> char* {
    char* p = ws + off;
    off = (off + bytes + 255) & ~(size_t)255;
    return p;
  };
  uint32_t* x2  = (uint32_t*)take((size_t)32768 * 128 * 4);    // 16 MiB
  uint32_t* W2  = (uint32_t*)take((size_t)4 * 128 * 1024 * 4); // 2 MiB
  uint16_t* UzT = (uint16_t*)take((size_t)1024 * 1024 * 2);    // 2 MiB
  uint16_t* UrT = (uint16_t*)take((size_t)1024 * 1024 * 2);
  uint16_t* UhT = (uint16_t*)take((size_t)1024 * 1024 * 2);
  uint16_t* g_gamma = (uint16_t*)take((size_t)NT * NB * NH * 2); // 64 MiB
  uint16_t* g_xz   = (uint16_t*)take((size_t)NT * NB * NH * 2);
  uint16_t* g_xr   = (uint16_t*)take((size_t)NT * NB * NH * 2);
  uint16_t* g_xh   = (uint16_t*)take((size_t)NT * NB * NH * 2);
  uint16_t* Hdat   = (uint16_t*)take((size_t)NB * NH * 2);     // 128 KiB
  uint16_t* RHdat  = (uint16_t*)take((size_t)NB * NH * 2);     // 128 KiB
  uint32_t* Htag   = (uint32_t*)take((size_t)8 * 32 * 16 * 4); // 16 KiB
  uint32_t* RHtag  = (uint32_t*)take((size_t)8 * 32 * 16 * 4); // 16 KiB
  (void)ws_size; (void)in_sizes; (void)n_in; (void)out_size;

  (void)hipMemsetAsync(Hdat, 0, (size_t)NB * NH * 2, stream);   // h(0) = 0
  (void)hipMemsetAsync(Htag, 0, (size_t)8 * 32 * 16 * 4, stream);  // tag 0 = ready(t=0)
  (void)hipMemsetAsync(RHtag, 0, (size_t)8 * 32 * 16 * 4, stream); // tag 0 (< 1)

  pack_x_k<<<2048, 256, 0, stream>>>((const float2*)x, x2, 32768 * 128);
  pack_rows_k<<<512, 256, 0, stream>>>(Wd, W2 + 0 * (128 * 1024), ND);
  pack_rows_k<<<512, 256, 0, stream>>>(Wz, W2 + 1 * (128 * 1024), ND);
  pack_rows_k<<<512, 256, 0, stream>>>(Wr, W2 + 2 * (128 * 1024), ND);
  pack_rows_k<<<512, 256, 0, stream>>>(Wh, W2 + 3 * (128 * 1024), ND);
  transpose_f2h_k<<<256, 256, 0, stream>>>(Uz, UzT);
  transpose_f2h_k<<<256, 256, 0, stream>>>(Ur, UrT);
  transpose_f2h_k<<<256, 256, 0, stream>>>(Uh, UhT);

  proj_k<<<32768, 256, 0, stream>>>(x2, W2, bd, bz, br, bh,
                                    g_gamma, g_xz, g_xr, g_xh);

  scan_k<<<256, 256, 0, stream>>>(UzT, UrT, UhT, g_gamma, g_xz, g_xr, g_xh,
                                  Hdat, RHdat, Htag, RHtag, out);
}